// Round 11
// baseline (101.039 us; speedup 1.0000x reference)
//
#include <hip/hip_runtime.h>
#include <hip/hip_bf16.h>

// Problem dims: x[b=8, c=64, h=64, w=64, t=12] fp32
// x float offsets: b*3145728 + c*49152 + h*768 + w*12 + t
//
// Scratch inside d_out (floats): [0,1600) = Weff[c*25 + tap], tap = dh*5+dw
// (read by k_conv5 before k_out overwrites d_out)
#define WEFF_OFF 0
// d_ws: p[m*12 + t], m = (b*64+h)*64+w   (1.57 MB)

// ---------------------------------------------------------------------------
// K1: fold 1x1-conv (key half of w1) into the 5x5 conv weights.
__global__ __launch_bounds__(256) void k_prep(const float* __restrict__ w1,
                                              const float* __restrict__ w2,
                                              float* __restrict__ weff) {
    int idx = blockIdx.x * 256 + threadIdx.x;
    if (idx >= 64 * 25) return;
    int cp = idx / 25, tap = idx % 25;
    float s = 0.f;
    for (int c = 0; c < 64; ++c)
        s = fmaf(w2[(64 + c) * 25 + tap], w1[(64 + c) * 64 + cp], s);
    weff[cp * 25 + tap] = s;
}

// ---------------------------------------------------------------------------
// K2 (k_conv5 v2): fused conv + softmax — register-pressure fix of R10.
// R10 had zz[5][12]=60 live accumulators vs VGPR_Count=52 => compiler spill
// in the inner loop (the 61us). Now: 960 thr = 3 t-thirds x 64 w x 5 dh;
// thread holds zz[5][4] = 20 accumulators (~40 VGPR, no spill, 8 waves/SIMD).
// Per channel: ONE float4 load (16B/lane, wave-contiguous) + 20 FMA.
// Same 5-turn LDS scatter to output cols w' = w+2-dw; dw-sum by dh0 group;
// softmax by one wave. Grid: 512 = 8 b(XCD) x 64 h; 2 blocks/CU exact.
__global__ __launch_bounds__(960) void k_conv5(const float* __restrict__ x,
                                               const float* __restrict__ weff,
                                               float* __restrict__ p) {
    __shared__ float lacc[64 * 65];   // [w'][dw*12+t], stride 65 -> conflict-free
    __shared__ float lsm[64 * 13];    // [w][t] for the softmax stage

    const int bid = blockIdx.x;
    const int b   = bid & 7;          // XCD-aligned batch
    const int h   = bid >> 3;
    const int tid = threadIdx.x;
    const int tt  = tid % 3;          // t-third: t = tt*4..tt*4+3
    const int w   = (tid / 3) & 63;
    const int dh  = tid / 192;        // 0..4, wave-uniform (192 = 3 waves)
    const int r   = h + dh - 2;

    for (int i = tid; i < 64 * 65; i += 960) lacc[i] = 0.f;

    float zz[5][4];
#pragma unroll
    for (int dw = 0; dw < 5; ++dw)
#pragma unroll
        for (int j = 0; j < 4; ++j) zz[dw][j] = 0.f;

    if ((unsigned)r < 64u) {
        // lane address = base + 16B*lane within each wave -> fully coalesced
        const float* xp = x + (size_t)b * 3145728 + r * 768 + w * 12 + tt * 4;
        const float* wgb = weff + dh * 5;          // wave-uniform
        for (int c = 0; c < 64; c += 2) {
            float4 v0 = *(const float4*)(xp + (size_t)c * 49152);
            float4 v1 = *(const float4*)(xp + (size_t)(c + 1) * 49152);
            const float* wg0 = wgb + c * 25;       // wave-uniform -> s_loads
            const float* wg1 = wg0 + 25;
#pragma unroll
            for (int dw = 0; dw < 5; ++dw) {
                const float g0 = wg0[dw];
                zz[dw][0] = fmaf(g0, v0.x, zz[dw][0]);
                zz[dw][1] = fmaf(g0, v0.y, zz[dw][1]);
                zz[dw][2] = fmaf(g0, v0.z, zz[dw][2]);
                zz[dw][3] = fmaf(g0, v0.w, zz[dw][3]);
            }
#pragma unroll
            for (int dw = 0; dw < 5; ++dw) {
                const float g1 = wg1[dw];
                zz[dw][0] = fmaf(g1, v1.x, zz[dw][0]);
                zz[dw][1] = fmaf(g1, v1.y, zz[dw][1]);
                zz[dw][2] = fmaf(g1, v1.z, zz[dw][2]);
                zz[dw][3] = fmaf(g1, v1.w, zz[dw][3]);
            }
        }
    }
    __syncthreads();

    // 5-turn deterministic cross-wave accumulation: input col w contributes
    // to output col w' = w+2-dw. Within a turn all active addresses distinct.
#pragma unroll
    for (int turn = 0; turn < 5; ++turn) {
        if (dh == turn) {
#pragma unroll
            for (int dw = 0; dw < 5; ++dw) {
                const int wp = w + 2 - dw;
                if ((unsigned)wp < 64u) {
                    float* a = lacc + wp * 65 + dw * 12 + tt * 4;
                    a[0] += zz[dw][0]; a[1] += zz[dw][1];
                    a[2] += zz[dw][2]; a[3] += zz[dw][3];
                }
            }
        }
        __syncthreads();
    }

    // dw-sum by the dh==0 group (192 threads cover (w,tt))
    if (dh == 0) {
        const float* lw = lacc + w * 65 + tt * 4;
        float* d = lsm + w * 13 + tt * 4;
#pragma unroll
        for (int j = 0; j < 4; ++j)
            d[j] = lw[j] + lw[12 + j] + lw[24 + j] + lw[36 + j] + lw[48 + j];
    }
    __syncthreads();

    // softmax over t by one wave (thread per w), write p
    if (tid < 64) {
        const int ww = tid;
        const float* lw = lsm + ww * 13;
        float v[12];
#pragma unroll
        for (int t = 0; t < 12; ++t) v[t] = lw[t];
        float mx = v[0];
#pragma unroll
        for (int t = 1; t < 12; ++t) mx = fmaxf(mx, v[t]);
        float s = 0.f;
#pragma unroll
        for (int t = 0; t < 12; ++t) { v[t] = __expf(v[t] - mx); s += v[t]; }
        const float inv = 1.f / s;
#pragma unroll
        for (int t = 0; t < 12; ++t) v[t] *= inv;
        float* op = p + (size_t)((b * 64 + h) * 64 + ww) * 12;
        float4 s0; s0.x = v[0]; s0.y = v[1]; s0.z = v[2];  s0.w = v[3];
        float4 s1; s1.x = v[4]; s1.y = v[5]; s1.z = v[6];  s1.w = v[7];
        float4 s2; s2.x = v[8]; s2.y = v[9]; s2.z = v[10]; s2.w = v[11];
        *(float4*)(op)     = s0;
        *(float4*)(op + 4) = s1;
        *(float4*)(op + 8) = s2;
    }
}

// ---------------------------------------------------------------------------
// K4: out[b,c,h,w,s] = W1v · (sum_t p_t * x[:,t]) + b1v, broadcast over s.
// One block per (b,h): 512 threads = 64 w-lanes * 8 channel-groups.
__global__ __launch_bounds__(512) void k_out(const float* __restrict__ x,
                                             const float* __restrict__ w1,
                                             const float* __restrict__ b1,
                                             const float* __restrict__ p,
                                             float* __restrict__ out) {
    __shared__ float lds[64 * 65];   // [w][c], padded -> conflict-free

    const int b  = blockIdx.x >> 6;
    const int h  = blockIdx.x & 63;
    const int w  = threadIdx.x & 63;
    const int cg = threadIdx.x >> 6;     // 0..7

    const float* pp = p + (size_t)((b * 64 + h) * 64 + w) * 12;
    float pv[12];
    {
        float4 t0 = *(const float4*)(pp);
        float4 t1 = *(const float4*)(pp + 4);
        float4 t2 = *(const float4*)(pp + 8);
        pv[0] = t0.x; pv[1] = t0.y; pv[2]  = t0.z; pv[3]  = t0.w;
        pv[4] = t1.x; pv[5] = t1.y; pv[6]  = t1.z; pv[7]  = t1.w;
        pv[8] = t2.x; pv[9] = t2.y; pv[10] = t2.z; pv[11] = t2.w;
    }

    const float* xb0 = x + ((size_t)(b * 64 + cg * 8) * 64 + h) * 768 + w * 12;
#pragma unroll
    for (int j = 0; j < 8; ++j) {
        const float* xp = xb0 + (size_t)j * 49152;
        float4 u0 = *(const float4*)(xp);
        float4 u1 = *(const float4*)(xp + 4);
        float4 u2 = *(const float4*)(xp + 8);
        float s = 0.f;
        s = fmaf(pv[0], u0.x, s);  s = fmaf(pv[1], u0.y, s);
        s = fmaf(pv[2], u0.z, s);  s = fmaf(pv[3], u0.w, s);
        s = fmaf(pv[4], u1.x, s);  s = fmaf(pv[5], u1.y, s);
        s = fmaf(pv[6], u1.z, s);  s = fmaf(pv[7], u1.w, s);
        s = fmaf(pv[8], u2.x, s);  s = fmaf(pv[9], u2.y, s);
        s = fmaf(pv[10], u2.z, s); s = fmaf(pv[11], u2.w, s);
        lds[w * 65 + cg * 8 + j] = s;
    }
    __syncthreads();

    const float* w1v = w1 + 128 * 64 + cg * 8 * 64;
    float acc[8];
#pragma unroll
    for (int j = 0; j < 8; ++j) acc[j] = b1[128 + cg * 8 + j];
    for (int c2 = 0; c2 < 64; ++c2) {
        const float xv = lds[w * 65 + c2];
#pragma unroll
        for (int j = 0; j < 8; ++j)
            acc[j] = fmaf(w1v[j * 64 + c2], xv, acc[j]);
    }

#pragma unroll
    for (int j = 0; j < 8; ++j) {
        const int co = cg * 8 + j;
        float4 f; f.x = acc[j]; f.y = acc[j]; f.z = acc[j]; f.w = acc[j];
        float* op = out + ((size_t)(b * 64 + co) * 4096 + h * 64 + w) * 12;
        *(float4*)(op)     = f;
        *(float4*)(op + 4) = f;
        *(float4*)(op + 8) = f;
    }
}

// ---------------------------------------------------------------------------
extern "C" void kernel_launch(void* const* d_in, const int* in_sizes, int n_in,
                              void* d_out, int out_size, void* d_ws, size_t ws_size,
                              hipStream_t stream) {
    const float* x  = (const float*)d_in[0];
    const float* w1 = (const float*)d_in[1];
    const float* b1 = (const float*)d_in[2];
    const float* w2 = (const float*)d_in[3];
    // d_in[4] = b2: constant across the softmax axis -> cancels, unused.

    float* outp = (float*)d_out;
    float* weff = outp + WEFF_OFF;   // 6.4 KB scratch in d_out, read before k_out
    float* p    = (float*)d_ws;      // 1.57 MB

    hipLaunchKernelGGL(k_prep,   dim3(7),   dim3(256), 0, stream, w1, w2, weff);
    hipLaunchKernelGGL(k_conv5,  dim3(512), dim3(960), 0, stream, x, weff, p);
    hipLaunchKernelGGL(k_out,    dim3(512), dim3(512), 0, stream, x, w1, b1, p, outp);
}